// Round 6
// baseline (197.231 us; speedup 1.0000x reference)
//
#include <hip/hip_runtime.h>
#include <stdint.h>

typedef unsigned short u16;
typedef short short4v __attribute__((ext_vector_type(4)));
typedef short short8v __attribute__((ext_vector_type(8)));
typedef float float4v __attribute__((ext_vector_type(4)));

#define AS1(p) ((__attribute__((address_space(1))) void*)(p))
#define AS3(p) ((__attribute__((address_space(3))) void*)(p))

#define MFMA32(a, b, c) __builtin_amdgcn_mfma_f32_16x16x32_bf16(a, b, c, 0, 0, 0)

static __device__ __forceinline__ float4v MFMA16(short4v a, short4v b, float4v c) {
#if __has_builtin(__builtin_amdgcn_mfma_f32_16x16x16bf16_1k)
  return __builtin_amdgcn_mfma_f32_16x16x16bf16_1k(a, b, c, 0, 0, 0);
#else
  float4v d;
  asm volatile("v_mfma_f32_16x16x16_bf16 %0, %1, %2, %3\n\ts_nop 7\n\ts_nop 3"
               : "=v"(d)
               : "v"(a), "v"(b), "v"(c));
  return d;
#endif
}

static __device__ __forceinline__ u16 f2bf(float f) {
  uint32_t u = __builtin_bit_cast(uint32_t, f);
  u += 0x7FFFu + ((u >> 16) & 1u);
  return (u16)(u >> 16);
}

static __device__ __forceinline__ unsigned cvtpk(float lo, float hi) {
  unsigned r;
  asm("v_cvt_pk_bf16_f32 %0, %1, %2" : "=v"(r) : "v"(lo), "v"(hi));
  return r;
}

#define TR4(v0_, v1_, v2_, v3_, addr_)                                   \
  asm volatile("ds_read_b64_tr_b16 %0, %4 offset:0\n\t"                  \
               "ds_read_b64_tr_b16 %1, %4 offset:2048\n\t"               \
               "ds_read_b64_tr_b16 %2, %4 offset:4096\n\t"               \
               "ds_read_b64_tr_b16 %3, %4 offset:6144\n\t"               \
               "s_waitcnt lgkmcnt(0)"                                    \
               : "=&v"(v0_), "=&v"(v1_), "=&v"(v2_), "=&v"(v3_)          \
               : "v"(addr_)                                              \
               : "memory")

// raw barriers for the attn pipeline (no vmcnt drain; T4)
#define ABAR() asm volatile("s_barrier" ::: "memory")
#define AVBAR(N) asm volatile("s_waitcnt vmcnt(" #N ")\n\ts_barrier" ::: "memory")

// ---------------- f32 -> bf16 casts ----------------

__global__ __launch_bounds__(256) void cast1_k(const float* __restrict__ s, u16* __restrict__ d) {
  const int i = (blockIdx.x * 256 + threadIdx.x) * 4;
  float4v v = *(const float4v*)(s + i);
  short4v o;
#pragma unroll
  for (int j = 0; j < 4; j++) o[j] = (short)f2bf(v[j]);
  *(short4v*)(d + i) = o;
}

__global__ __launch_bounds__(256) void cast4_k(const float* __restrict__ s0, const float* __restrict__ s1,
                                               const float* __restrict__ s2, const float* __restrict__ s3,
                                               u16* __restrict__ d0, u16* __restrict__ d1,
                                               u16* __restrict__ d2, u16* __restrict__ d3) {
  const float* s;
  u16* d;
  switch (blockIdx.y) {
    case 0: s = s0; d = d0; break;
    case 1: s = s1; d = d1; break;
    case 2: s = s2; d = d2; break;
    default: s = s3; d = d3; break;
  }
  const int i = (blockIdx.x * 256 + threadIdx.x) * 4;
  float4v v = *(const float4v*)(s + i);
  short4v o;
#pragma unroll
  for (int j = 0; j < 4; j++) o[j] = (short)f2bf(v[j]);
  *(short4v*)(d + i) = o;
}

// ---------------- 256x256-tile 8-wave pipelined GEMM (QKV) ----------------

__global__ __launch_bounds__(512, 2) void gemm256(
    const u16* __restrict__ A,
    const u16* __restrict__ B0, const u16* __restrict__ B1, const u16* __restrict__ B2,
    const float* __restrict__ bias0, const float* __restrict__ bias1, const float* __restrict__ bias2,
    u16* __restrict__ C0, u16* __restrict__ C1, u16* __restrict__ C2,
    float sc0, float sc1, float sc2) {
  constexpr int K = 1024;
  __shared__ u16 As[4][256][32];
  __shared__ u16 Bs[4][256][32];

  const int t = threadIdx.x;
  const int lane = t & 63, wid = t >> 6;
  const int wm = wid >> 2, wn = wid & 3;
  const int lr = lane & 15, g = lane >> 4;

  const int id = blockIdx.x;
  const int xc = id & 7, off = id >> 3;
  const int mb = (xc & 3) * 4 + (off & 3);
  const int nbt = (xc >> 2) * 6 + (off >> 2);
  const int seg = nbt >> 2, nb = nbt & 3;

  const u16* Bm = seg == 0 ? B0 : (seg == 1 ? B1 : B2);
  const float* bias = seg == 0 ? bias0 : (seg == 1 ? bias1 : bias2);
  u16* C = seg == 0 ? C0 : (seg == 1 ? C1 : C2);
  const float scale = seg == 0 ? sc0 : (seg == 1 ? sc1 : sc2);

  const u16* Ap = A + (size_t)mb * 256 * K;
  const u16* Bp = Bm + (size_t)nb * 256 * K;

  float4v z = {0.f, 0.f, 0.f, 0.f};
  float4v acc[8][4];
#pragma unroll
  for (int i = 0; i < 8; i++)
#pragma unroll
    for (int j = 0; j < 4; j++) acc[i][j] = z;

  const int sr0 = t >> 2, sr1 = sr0 + 128;
  const int pc = (t & 3) * 8;
  const int scol = ((t & 3) ^ ((t >> 3) & 3)) * 8;

#define STGA(rg, kb)                                                                                            \
  {                                                                                                             \
    __builtin_amdgcn_global_load_lds(AS1(Ap + (size_t)sr0 * K + (kb) + scol), AS3(&As[rg][sr0][pc]), 16, 0, 0); \
    __builtin_amdgcn_global_load_lds(AS1(Ap + (size_t)sr1 * K + (kb) + scol), AS3(&As[rg][sr1][pc]), 16, 0, 0); \
  }
#define STGB(rg, kb)                                                                                            \
  {                                                                                                             \
    __builtin_amdgcn_global_load_lds(AS1(Bp + (size_t)sr0 * K + (kb) + scol), AS3(&Bs[rg][sr0][pc]), 16, 0, 0); \
    __builtin_amdgcn_global_load_lds(AS1(Bp + (size_t)sr1 * K + (kb) + scol), AS3(&Bs[rg][sr1][pc]), 16, 0, 0); \
  }
#define VM8 asm volatile("s_waitcnt vmcnt(8)" ::: "memory")
#define VM4 asm volatile("s_waitcnt vmcnt(4)" ::: "memory")
#define VM0 asm volatile("s_waitcnt vmcnt(0)" ::: "memory")

#define PH(rg, mq, STG_, VM_)                                                         \
  {                                                                                   \
    short8v a_[4], b_[4];                                                             \
    _Pragma("unroll") for (int i = 0; i < 4; i++) {                                   \
      const int r_ = wm * 128 + ((mq)*4 + i) * 16 + lr;                               \
      a_[i] = *(const short8v*)&As[rg][r_][(g ^ ((r_ >> 1) & 3)) * 8];                \
    }                                                                                 \
    _Pragma("unroll") for (int j = 0; j < 4; j++) {                                   \
      const int r_ = wn * 64 + j * 16 + lr;                                           \
      b_[j] = *(const short8v*)&Bs[rg][r_][(g ^ ((r_ >> 1) & 3)) * 8];                \
    }                                                                                 \
    STG_;                                                                             \
    VM_;                                                                              \
    __builtin_amdgcn_s_barrier();                                                     \
    asm volatile("s_waitcnt lgkmcnt(0)");                                             \
    __builtin_amdgcn_sched_barrier(0);                                                \
    __builtin_amdgcn_s_setprio(1);                                                    \
    _Pragma("unroll") for (int i = 0; i < 4; i++)                                     \
        _Pragma("unroll") for (int j = 0; j < 4; j++)                                 \
            acc[(mq)*4 + i][j] = MFMA32(a_[i], b_[j], acc[(mq)*4 + i][j]);            \
    __builtin_amdgcn_s_setprio(0);                                                    \
    __builtin_amdgcn_s_barrier();                                                     \
  }

  STGA(0, 0);
  STGB(0, 0);
  STGA(1, 32);
  STGB(1, 32);
  STGA(2, 64);
  STGB(2, 64);
  VM8;
  __builtin_amdgcn_s_barrier();

  for (int r = 0; r < 29; ++r) {
    const int rg = r & 3, rs = (r + 3) & 3, kb = (r + 3) * 32;
    PH(rg, 0, STGA(rs, kb), );
    PH(rg, 1, STGB(rs, kb), VM8);
  }
  PH(1, 0, , );
  PH(1, 1, , VM4);
  PH(2, 0, , );
  PH(2, 1, , VM0);
  PH(3, 0, , );
  PH(3, 1, , );

#undef PH
#undef STGA
#undef STGB

  const int colb = nb * 256 + wn * 64;
  const int rowb = mb * 256 + wm * 128;
#pragma unroll
  for (int j = 0; j < 4; j++) {
    const int col = colb + j * 16 + lr;
    const float bv = bias[col];
#pragma unroll
    for (int i = 0; i < 8; i++) {
      const int row0 = rowb + i * 16 + g * 4;
#pragma unroll
      for (int r = 0; r < 4; r++)
        C[(size_t)(row0 + r) * 1024 + col] = f2bf((acc[i][j][r] + bv) * scale);
    }
  }
}

// ---------------- GEMM (output projection): 128x128 tile, 2-phase dbuf ----------------

template <int OUTF32>
__global__ __launch_bounds__(256) void gemm_bt(
    const u16* __restrict__ A,
    const u16* __restrict__ B0, const u16* __restrict__ B1, const u16* __restrict__ B2,
    const float* __restrict__ bias0, const float* __restrict__ bias1, const float* __restrict__ bias2,
    void* __restrict__ C0, void* __restrict__ C1, void* __restrict__ C2,
    float sc0, float sc1, float sc2) {
  constexpr int K = 1024;
  __shared__ u16 As[2][128 * 32];
  __shared__ u16 Bs[2][128 * 32];

  const int t = threadIdx.x;
  const int lane = t & 63, wid = t >> 6;
  const int wr = wid >> 1, wc = wid & 1;
  const int lr = lane & 15, g = lane >> 4;

  const int seg = blockIdx.y >> 3, nb = blockIdx.y & 7, mb = blockIdx.x;
  const u16* B = seg == 0 ? B0 : (seg == 1 ? B1 : B2);
  const float* bias = seg == 0 ? bias0 : (seg == 1 ? bias1 : bias2);
  void* C = seg == 0 ? C0 : (seg == 1 ? C1 : C2);
  const float scale = seg == 0 ? sc0 : (seg == 1 ? sc1 : sc2);

  const u16* Ap = A + (size_t)mb * 128 * K;
  const u16* Bp = B + (size_t)nb * 128 * K;

  float4v z = {0.f, 0.f, 0.f, 0.f};
  float4v acc[4][4];
#pragma unroll
  for (int i = 0; i < 4; i++)
#pragma unroll
    for (int j = 0; j < 4; j++) acc[i][j] = z;

  const int r0 = t >> 2, c0 = (t & 3) * 8;

#define GSTAGE(u, kk)                                                                                          \
  do {                                                                                                         \
    __builtin_amdgcn_global_load_lds(AS1(Ap + (size_t)r0 * K + (kk) + c0), AS3(&As[u][t * 8]), 16, 0, 0);      \
    __builtin_amdgcn_global_load_lds(AS1(Ap + (size_t)(r0 + 64) * K + (kk) + c0), AS3(&As[u][(t + 256) * 8]),  \
                                     16, 0, 0);                                                                \
    __builtin_amdgcn_global_load_lds(AS1(Bp + (size_t)r0 * K + (kk) + c0), AS3(&Bs[u][t * 8]), 16, 0, 0);      \
    __builtin_amdgcn_global_load_lds(AS1(Bp + (size_t)(r0 + 64) * K + (kk) + c0), AS3(&Bs[u][(t + 256) * 8]),  \
                                     16, 0, 0);                                                                \
  } while (0)

  GSTAGE(0, 0);
  int cur = 0;
  for (int k0 = 0; k0 < K; k0 += 32) {
    __syncthreads();
    if (k0 + 32 < K) GSTAGE(cur ^ 1, k0 + 32);

    const u16* Au = &As[cur][0];
    const u16* Bu = &Bs[cur][0];
    short8v af[4], bfr[4];
#pragma unroll
    for (int mi = 0; mi < 4; mi++) af[mi] = *(const short8v*)(Au + (wr * 64 + mi * 16 + lr) * 32 + g * 8);
#pragma unroll
    for (int ni = 0; ni < 4; ni++) bfr[ni] = *(const short8v*)(Bu + (wc * 64 + ni * 16 + lr) * 32 + g * 8);
    __builtin_amdgcn_s_setprio(1);
#pragma unroll
    for (int mi = 0; mi < 4; mi++)
#pragma unroll
      for (int ni = 0; ni < 4; ni++) acc[mi][ni] = MFMA32(af[mi], bfr[ni], acc[mi][ni]);
    __builtin_amdgcn_s_setprio(0);
    __syncthreads();
    cur ^= 1;
  }
#undef GSTAGE

  const int colb = nb * 128 + wc * 64;
  const int rowb = mb * 128 + wr * 64;
#pragma unroll
  for (int ni = 0; ni < 4; ni++) {
    const int col = colb + ni * 16 + lr;
    const float bv = bias[col];
#pragma unroll
    for (int mi = 0; mi < 4; mi++) {
      const int row0 = rowb + mi * 16 + g * 4;
      float4v a = acc[mi][ni];
      if (OUTF32) {
        float* Cf = (float*)C;
#pragma unroll
        for (int r = 0; r < 4; r++) Cf[(size_t)(row0 + r) * 1024 + col] = (a[r] + bv) * scale;
      } else {
        u16* Cb = (u16*)C;
#pragma unroll
        for (int r = 0; r < 4; r++) Cb[(size_t)(row0 + r) * 1024 + col] = f2bf((a[r] + bv) * scale);
      }
    }
  }
}

// ---------------- Flash attention — software-pipelined (T3/T4/T15) ----------------
// Ring-3 LDS; steady state: QK^T(t+1) | PV(t) | bar | stage(t+3) | softmax(t+1)
// | vmcnt(4)+bar. Softmax serial chain is sandwiched between MFMA bursts;
// staging covered by a full iteration; vmcnt never drains to 0 mid-loop.

__global__ __launch_bounds__(256) void attn_fwd(const u16* __restrict__ Qm, const u16* __restrict__ Km,
                                                const u16* __restrict__ Vm, u16* __restrict__ Om) {
  __shared__ u16 Ks[3][64 * 64];
  __shared__ u16 Vs[3][64 * 64];

  const int t = threadIdx.x;
  const int lane = t & 63, w = t >> 6;
  const int lr = lane & 15, g = lane >> 4;
  const int qb = blockIdx.x, pair = blockIdx.y;
  const int b = pair >> 4, a = pair & 15;

  const int qrow = qb * 64 + w * 16 + lr;
  const size_t qoff = ((size_t)(b * 1024 + qrow)) * 1024 + a * 64;
  const short8v qf0 = *(const short8v*)(Qm + qoff + g * 8);
  const short8v qf1 = *(const short8v*)(Qm + qoff + 32 + g * 8);

  float4v z = {0.f, 0.f, 0.f, 0.f};
  float4v ot[4];
#pragma unroll
  for (int i = 0; i < 4; i++) ot[i] = z;
  float mrun = -3.0e38f, lsum = 0.f;

  const u16* Kb = Km + ((size_t)b * 1024) * 1024 + a * 64;
  const u16* Vb = Vm + ((size_t)b * 1024) * 1024 + a * 64;

  const int kr0 = t >> 3, kr1 = kr0 + 32;
  const int kc0 = ((t & 7) ^ (kr0 & 7)) * 8;
  const int vr0 = (t >> 1) & 63;
  const int vc0 = (t >> 7) * 16 + (t & 1) * 8;

#define ASTAGE(u, kt)                                                                                             \
  do {                                                                                                            \
    __builtin_amdgcn_global_load_lds(AS1(Kb + (size_t)((kt) + kr0) * 1024 + kc0), AS3(&Ks[u][t * 8]), 16, 0, 0);  \
    __builtin_amdgcn_global_load_lds(AS1(Kb + (size_t)((kt) + kr1) * 1024 + kc0), AS3(&Ks[u][(t + 256) * 8]),     \
                                     16, 0, 0);                                                                   \
    __builtin_amdgcn_global_load_lds(AS1(Vb + (size_t)((kt) + vr0) * 1024 + vc0), AS3(&Vs[u][t * 8]), 16, 0, 0);  \
    __builtin_amdgcn_global_load_lds(AS1(Vb + (size_t)((kt) + vr0) * 1024 + vc0 + 32), AS3(&Vs[u][(t + 256) * 8]),\
                                     16, 0, 0);                                                                   \
  } while (0)

  const unsigned vsbase = (unsigned)(uintptr_t)AS3(&Vs[0][0]);
  const unsigned vlane = (unsigned)((g * 4 + (lr >> 2)) * 32 + (lane & 3) * 8);

  float4v st[4];
  short4v pf[4];

  // QK^T of tile in ring rc -> st
#define AQKT(rc)                                                                 \
  {                                                                              \
    const char* Kbase = (const char*)&Ks[rc][0];                                 \
    __builtin_amdgcn_s_setprio(1);                                               \
    _Pragma("unroll") for (int jt = 0; jt < 4; jt++) {                           \
      const int row = jt * 16 + lr;                                              \
      const int rsw = (row & 7) << 4;                                            \
      short8v kf0 = *(const short8v*)(Kbase + ((row * 128 + g * 16) ^ rsw));     \
      short8v kf1 = *(const short8v*)(Kbase + ((row * 128 + (4 + g) * 16) ^ rsw));\
      float4v s = MFMA32(kf0, qf0, z);                                           \
      s = MFMA32(kf1, qf1, s);                                                   \
      st[jt] = s;                                                                \
    }                                                                            \
    __builtin_amdgcn_s_setprio(0);                                               \
  }

  // online softmax on st -> pf, updates mrun/lsum/ot-rescale
#define ASM_()                                                                   \
  {                                                                              \
    float m0 = fmaxf(fmaxf(st[0][0], st[0][1]), fmaxf(st[0][2], st[0][3]));      \
    float m1 = fmaxf(fmaxf(st[1][0], st[1][1]), fmaxf(st[1][2], st[1][3]));      \
    float m2 = fmaxf(fmaxf(st[2][0], st[2][1]), fmaxf(st[2][2], st[2][3]));      \
    float m3 = fmaxf(fmaxf(st[3][0], st[3][1]), fmaxf(st[3][2], st[3][3]));      \
    float tm = fmaxf(fmaxf(m0, m1), fmaxf(m2, m3));                              \
    tm = fmaxf(tm, __shfl_xor(tm, 16));                                          \
    tm = fmaxf(tm, __shfl_xor(tm, 32));                                          \
    if (!__all(tm - mrun <= 8.f)) {                                              \
      const float mnew = fmaxf(mrun, tm);                                        \
      const float sca = exp2f(mrun - mnew);                                      \
      lsum *= sca;                                                               \
      _Pragma("unroll") for (int d = 0; d < 4; d++)                              \
          _Pragma("unroll") for (int r = 0; r < 4; r++) ot[d][r] *= sca;         \
      mrun = mnew;                                                               \
    }                                                                            \
    float p[16];                                                                 \
    _Pragma("unroll") for (int jt = 0; jt < 4; jt++)                             \
        _Pragma("unroll") for (int r = 0; r < 4; r++)                            \
            p[jt * 4 + r] = exp2f(st[jt][r] - mrun);                             \
    float q0 = (p[0] + p[1]) + (p[2] + p[3]);                                    \
    float q1 = (p[4] + p[5]) + (p[6] + p[7]);                                    \
    float q2 = (p[8] + p[9]) + (p[10] + p[11]);                                  \
    float q3 = (p[12] + p[13]) + (p[14] + p[15]);                                \
    float ts = (q0 + q1) + (q2 + q3);                                            \
    ts += __shfl_xor(ts, 16);                                                    \
    ts += __shfl_xor(ts, 32);                                                    \
    lsum += ts;                                                                  \
    _Pragma("unroll") for (int jt = 0; jt < 4; jt++) {                           \
      unsigned lo = cvtpk(p[jt * 4 + 0], p[jt * 4 + 1]);                         \
      unsigned hi = cvtpk(p[jt * 4 + 2], p[jt * 4 + 3]);                         \
      unsigned u2[2] = {lo, hi};                                                 \
      pf[jt] = __builtin_bit_cast(short4v, *(unsigned long long*)u2);            \
    }                                                                            \
  }

  // PV from ring rc using pf
#define APV(rc)                                                                  \
  {                                                                              \
    unsigned va = vsbase + (unsigned)(rc)*8192u + vlane;                         \
    _Pragma("unroll") for (int jt = 0; jt < 4; jt++) {                           \
      short4v vf0, vf1, vf2, vf3;                                                \
      TR4(vf0, vf1, vf2, vf3, va);                                               \
      __builtin_amdgcn_s_setprio(1);                                             \
      ot[0] = MFMA16(vf0, pf[jt], ot[0]);                                        \
      ot[1] = MFMA16(vf1, pf[jt], ot[1]);                                        \
      ot[2] = MFMA16(vf2, pf[jt], ot[2]);                                        \
      ot[3] = MFMA16(vf3, pf[jt], ot[3]);                                        \
      __builtin_amdgcn_s_setprio(0);                                             \
      va += 512u;                                                                \
    }                                                                            \
  }

  // ---- prologue: stage tiles 0,1,2; compute QK^T(0), softmax(0) ----
  ASTAGE(0, 0);
  ASTAGE(1, 64);
  ASTAGE(2, 128);
  AVBAR(8);  // tile0 landed (collective)
  AQKT(0);
  ASM_();
  AVBAR(4);  // tile1 landed

  // ---- steady state: tiles 0..12 (uniform) ----
  for (int tt = 0; tt < 13; ++tt) {
    const int rc = tt % 3, rn = (tt + 1) % 3;
    AQKT(rn);           // QK^T(t+1): independent MFMA burst after softmax(t)
    APV(rc);            // PV(t): consumes pf(t) after QK^T-issue gap
    ABAR();             // all readers of ring rc done
    ASTAGE(rc, (tt + 3) * 64);  // stage tile t+3 into freed slot
    ASM_();             // softmax(t+1) -> pf(t+1), covered by PV+stage
    AVBAR(4);           // tile t+2 landed
  }
  // ---- tail: t=13 ----
  AQKT(2);   // QK^T(14)
  APV(1);    // PV(13)
  ABAR();
  ASM_();    // softmax(14)
  AVBAR(0);  // tile15 landed
  // ---- tail: t=14 ----
  AQKT(0);   // QK^T(15)
  APV(2);    // PV(14)
  ASM_();    // softmax(15)
  APV(0);    // PV(15)

#undef ASTAGE
#undef AQKT
#undef ASM_
#undef APV

  const float inv = 1.f / lsum;
  u16* Op = Om + ((size_t)(b * 1024 + qrow)) * 1024 + a * 64;
#pragma unroll
  for (int dblk = 0; dblk < 4; dblk++) {
    short4v o4;
#pragma unroll
    for (int r = 0; r < 4; r++) o4[r] = (short)f2bf(ot[dblk][r] * inv);
    *(short4v*)(Op + dblk * 16 + g * 4) = o4;
  }
}

// ---------------- launch ----------------

extern "C" void kernel_launch(void* const* d_in, const int* in_sizes, int n_in,
                              void* d_out, int out_size, void* d_ws, size_t ws_size,
                              hipStream_t stream) {
  (void)in_sizes; (void)n_in; (void)out_size; (void)ws_size;
  const float* x = (const float*)d_in[0];
  const float* Wq = (const float*)d_in[1];
  const float* bq = (const float*)d_in[2];
  const float* Wk = (const float*)d_in[3];
  const float* bk = (const float*)d_in[4];
  const float* Wv = (const float*)d_in[5];
  const float* bv = (const float*)d_in[6];
  const float* Wo = (const float*)d_in[7];
  const float* bo = (const float*)d_in[8];
  float* out = (float*)d_out;

  char* ws = (char*)d_ws;
  const size_t MB = 1u << 20;
  u16* xb = (u16*)(ws + 0 * MB);
  u16* Wqb = (u16*)(ws + 8 * MB);
  u16* Wkb = (u16*)(ws + 10 * MB);
  u16* Wvb = (u16*)(ws + 12 * MB);
  u16* Wob = (u16*)(ws + 14 * MB);
  u16* Qb = (u16*)(ws + 16 * MB);
  u16* Kb = (u16*)(ws + 24 * MB);
  u16* Vb = (u16*)(ws + 32 * MB);
  u16* Ab = (u16*)(ws + 40 * MB);

  const float csc = 1.4426950408889634f / 8.0f;  // log2(e)/sqrt(HEAD_DIM)

  cast1_k<<<4096, 256, 0, stream>>>(x, xb);
  cast4_k<<<dim3(1024, 4), 256, 0, stream>>>(Wq, Wk, Wv, Wo, Wqb, Wkb, Wvb, Wob);
  gemm256<<<192, 512, 0, stream>>>(xb, Wqb, Wkb, Wvb, bq, bk, bv, Qb, Kb, Vb, csc, 1.f, 1.f);
  attn_fwd<<<dim3(16, 64), 256, 0, stream>>>(Qb, Kb, Vb, Ab);
  gemm_bt<1><<<dim3(32, 8), 256, 0, stream>>>(Ab, Wob, Wob, Wob, bo, bo, bo, out, out, out, 1.f, 1.f, 1.f);
}

// Round 7
// 185.089 us; speedup vs baseline: 1.0656x; 1.0656x over previous
//
#include <hip/hip_runtime.h>
#include <stdint.h>

typedef unsigned short u16;
typedef short short4v __attribute__((ext_vector_type(4)));
typedef short short8v __attribute__((ext_vector_type(8)));
typedef float float4v __attribute__((ext_vector_type(4)));

#define AS1(p) ((__attribute__((address_space(1))) void*)(p))
#define AS3(p) ((__attribute__((address_space(3))) void*)(p))

#define MFMA32(a, b, c) __builtin_amdgcn_mfma_f32_16x16x32_bf16(a, b, c, 0, 0, 0)

static __device__ __forceinline__ float4v MFMA16(short4v a, short4v b, float4v c) {
#if __has_builtin(__builtin_amdgcn_mfma_f32_16x16x16bf16_1k)
  return __builtin_amdgcn_mfma_f32_16x16x16bf16_1k(a, b, c, 0, 0, 0);
#else
  float4v d;
  asm volatile("v_mfma_f32_16x16x16_bf16 %0, %1, %2, %3\n\ts_nop 7\n\ts_nop 3"
               : "=v"(d)
               : "v"(a), "v"(b), "v"(c));
  return d;
#endif
}

static __device__ __forceinline__ u16 f2bf(float f) {
  uint32_t u = __builtin_bit_cast(uint32_t, f);
  u += 0x7FFFu + ((u >> 16) & 1u);
  return (u16)(u >> 16);
}

static __device__ __forceinline__ unsigned cvtpk(float lo, float hi) {
  unsigned r;
  asm("v_cvt_pk_bf16_f32 %0, %1, %2" : "=v"(r) : "v"(lo), "v"(hi));
  return r;
}

#define TR4(v0_, v1_, v2_, v3_, addr_)                                   \
  asm volatile("ds_read_b64_tr_b16 %0, %4 offset:0\n\t"                  \
               "ds_read_b64_tr_b16 %1, %4 offset:2048\n\t"               \
               "ds_read_b64_tr_b16 %2, %4 offset:4096\n\t"               \
               "ds_read_b64_tr_b16 %3, %4 offset:6144\n\t"               \
               "s_waitcnt lgkmcnt(0)"                                    \
               : "=&v"(v0_), "=&v"(v1_), "=&v"(v2_), "=&v"(v3_)          \
               : "v"(addr_)                                              \
               : "memory")

// ---------------- fused f32 -> bf16 casts (one launch for all 5 arrays) ----------------

__global__ __launch_bounds__(256) void cast_all(
    const float* __restrict__ x,
    const float* __restrict__ w0, const float* __restrict__ w1,
    const float* __restrict__ w2, const float* __restrict__ w3,
    u16* __restrict__ dx,
    u16* __restrict__ d0, u16* __restrict__ d1,
    u16* __restrict__ d2, u16* __restrict__ d3) {
  const int y = blockIdx.y;
  const float* s;
  u16* d;
  if (y == 0) {
    s = x;
    d = dx;
  } else {
    if (blockIdx.x >= 1024) return;  // W arrays are 1M elems (1024 blocks)
    switch (y) {
      case 1: s = w0; d = d0; break;
      case 2: s = w1; d = d1; break;
      case 3: s = w2; d = d2; break;
      default: s = w3; d = d3; break;
    }
  }
  const int i = (blockIdx.x * 256 + threadIdx.x) * 4;
  float4v v = *(const float4v*)(s + i);
  short4v o;
#pragma unroll
  for (int j = 0; j < 4; j++) o[j] = (short)f2bf(v[j]);
  *(short4v*)(d + i) = o;
}

// ---------------- QKV GEMM: 128x128 tile, BK=32, 2-phase dbuf ----------------
// C[m,n] = (sum_k A[m,k]*B[n,k] + bias[n]) * scale, bf16 out.

__global__ __launch_bounds__(256) void gemm_bt(
    const u16* __restrict__ A,
    const u16* __restrict__ B0, const u16* __restrict__ B1, const u16* __restrict__ B2,
    const float* __restrict__ bias0, const float* __restrict__ bias1, const float* __restrict__ bias2,
    u16* __restrict__ C0, u16* __restrict__ C1, u16* __restrict__ C2,
    float sc0, float sc1, float sc2) {
  constexpr int K = 1024;
  __shared__ u16 As[2][128 * 32];
  __shared__ u16 Bs[2][128 * 32];

  const int t = threadIdx.x;
  const int lane = t & 63, wid = t >> 6;
  const int wr = wid >> 1, wc = wid & 1;
  const int lr = lane & 15, g = lane >> 4;

  const int seg = blockIdx.y >> 3, nb = blockIdx.y & 7, mb = blockIdx.x;
  const u16* B = seg == 0 ? B0 : (seg == 1 ? B1 : B2);
  const float* bias = seg == 0 ? bias0 : (seg == 1 ? bias1 : bias2);
  u16* C = seg == 0 ? C0 : (seg == 1 ? C1 : C2);
  const float scale = seg == 0 ? sc0 : (seg == 1 ? sc1 : sc2);

  const u16* Ap = A + (size_t)mb * 128 * K;
  const u16* Bp = B + (size_t)nb * 128 * K;

  float4v z = {0.f, 0.f, 0.f, 0.f};
  float4v acc[4][4];
#pragma unroll
  for (int i = 0; i < 4; i++)
#pragma unroll
    for (int j = 0; j < 4; j++) acc[i][j] = z;

  const int r0 = t >> 2, c0 = (t & 3) * 8;

#define GSTAGE(u, kk)                                                                                          \
  do {                                                                                                         \
    __builtin_amdgcn_global_load_lds(AS1(Ap + (size_t)r0 * K + (kk) + c0), AS3(&As[u][t * 8]), 16, 0, 0);      \
    __builtin_amdgcn_global_load_lds(AS1(Ap + (size_t)(r0 + 64) * K + (kk) + c0), AS3(&As[u][(t + 256) * 8]),  \
                                     16, 0, 0);                                                                \
    __builtin_amdgcn_global_load_lds(AS1(Bp + (size_t)r0 * K + (kk) + c0), AS3(&Bs[u][t * 8]), 16, 0, 0);      \
    __builtin_amdgcn_global_load_lds(AS1(Bp + (size_t)(r0 + 64) * K + (kk) + c0), AS3(&Bs[u][(t + 256) * 8]),  \
                                     16, 0, 0);                                                                \
  } while (0)

  GSTAGE(0, 0);
  int cur = 0;
  for (int k0 = 0; k0 < K; k0 += 32) {
    __syncthreads();
    if (k0 + 32 < K) GSTAGE(cur ^ 1, k0 + 32);

    const u16* Au = &As[cur][0];
    const u16* Bu = &Bs[cur][0];
    short8v af[4], bfr[4];
#pragma unroll
    for (int mi = 0; mi < 4; mi++) af[mi] = *(const short8v*)(Au + (wr * 64 + mi * 16 + lr) * 32 + g * 8);
#pragma unroll
    for (int ni = 0; ni < 4; ni++) bfr[ni] = *(const short8v*)(Bu + (wc * 64 + ni * 16 + lr) * 32 + g * 8);
    __builtin_amdgcn_s_setprio(1);
#pragma unroll
    for (int mi = 0; mi < 4; mi++)
#pragma unroll
      for (int ni = 0; ni < 4; ni++) acc[mi][ni] = MFMA32(af[mi], bfr[ni], acc[mi][ni]);
    __builtin_amdgcn_s_setprio(0);
    __syncthreads();
    cur ^= 1;
  }
#undef GSTAGE

  const int colb = nb * 128 + wc * 64;
  const int rowb = mb * 128 + wr * 64;
#pragma unroll
  for (int ni = 0; ni < 4; ni++) {
    const int col = colb + ni * 16 + lr;
    const float bv = bias[col];
#pragma unroll
    for (int mi = 0; mi < 4; mi++) {
      const int row0 = rowb + mi * 16 + g * 4;
      float4v a = acc[mi][ni];
#pragma unroll
      for (int r = 0; r < 4; r++) C[(size_t)(row0 + r) * 1024 + col] = f2bf((a[r] + bv) * scale);
    }
  }
}

// ---------------- O-projection GEMM: 64x64 tile, BK=32, 2-phase dbuf ----------------
// grid 64x16 = 1024 blocks = 4 blocks/CU (16 waves/CU) -> TLP hides the
// barrier/staging drains that were fully exposed at 1 block/CU with 128^2.
// f32 output + bias.

__global__ __launch_bounds__(256) void gemm_o64(const u16* __restrict__ A, const u16* __restrict__ B,
                                                const float* __restrict__ bias, float* __restrict__ C) {
  constexpr int K = 1024;
  __shared__ u16 As[2][64 * 32];
  __shared__ u16 Bs[2][64 * 32];

  const int t = threadIdx.x;
  const int lane = t & 63, wid = t >> 6;
  const int wr = wid >> 1, wc = wid & 1;  // 2x2 waves; wave tile 32x32
  const int lr = lane & 15, g = lane >> 4;

  const int mb = blockIdx.x, nb = blockIdx.y;
  const u16* Ap = A + (size_t)mb * 64 * K;
  const u16* Bp = B + (size_t)nb * 64 * K;

  float4v z = {0.f, 0.f, 0.f, 0.f};
  float4v acc[2][2];
#pragma unroll
  for (int i = 0; i < 2; i++)
#pragma unroll
    for (int j = 0; j < 2; j++) acc[i][j] = z;

  const int r0 = t >> 2, c0 = (t & 3) * 8;  // one 16B chunk each for A and B

#define OSTAGE(u, kk)                                                                                       \
  do {                                                                                                      \
    __builtin_amdgcn_global_load_lds(AS1(Ap + (size_t)r0 * K + (kk) + c0), AS3(&As[u][t * 8]), 16, 0, 0);   \
    __builtin_amdgcn_global_load_lds(AS1(Bp + (size_t)r0 * K + (kk) + c0), AS3(&Bs[u][t * 8]), 16, 0, 0);   \
  } while (0)

  OSTAGE(0, 0);
  int cur = 0;
  for (int k0 = 0; k0 < K; k0 += 32) {
    __syncthreads();
    if (k0 + 32 < K) OSTAGE(cur ^ 1, k0 + 32);

    const u16* Au = &As[cur][0];
    const u16* Bu = &Bs[cur][0];
    short8v af[2], bfr[2];
#pragma unroll
    for (int mi = 0; mi < 2; mi++) af[mi] = *(const short8v*)(Au + (wr * 32 + mi * 16 + lr) * 32 + g * 8);
#pragma unroll
    for (int ni = 0; ni < 2; ni++) bfr[ni] = *(const short8v*)(Bu + (wc * 32 + ni * 16 + lr) * 32 + g * 8);
    __builtin_amdgcn_s_setprio(1);
#pragma unroll
    for (int mi = 0; mi < 2; mi++)
#pragma unroll
      for (int ni = 0; ni < 2; ni++) acc[mi][ni] = MFMA32(af[mi], bfr[ni], acc[mi][ni]);
    __builtin_amdgcn_s_setprio(0);
    __syncthreads();
    cur ^= 1;
  }
#undef OSTAGE

  const int colb = nb * 64 + wc * 32;
  const int rowb = mb * 64 + wr * 32;
#pragma unroll
  for (int ni = 0; ni < 2; ni++) {
    const int col = colb + ni * 16 + lr;
    const float bv = bias[col];
#pragma unroll
    for (int mi = 0; mi < 2; mi++) {
      const int row0 = rowb + mi * 16 + g * 4;
#pragma unroll
      for (int r = 0; r < 4; r++) C[(size_t)(row0 + r) * 1024 + col] = acc[mi][ni][r] + bv;
    }
  }
}

// ---------------- Flash attention (R2 config: QBLK=64, KVBLK=64, dbuf) ----------------
// Q pre-scaled by log2(e)/sqrt(64) in the QKV GEMM. S^T = mfma(K,Q) so each
// lane owns 16 P-values of one q-row; softmax reduce = in-register + 2
// shfl_xor. PV via mfma16 with V^T A-frags from ds_read_b64_tr_b16 out of a
// [dblk][64][16] subtiled V (linear LDS dest, permuted global source).

__global__ __launch_bounds__(256) void attn_fwd(const u16* __restrict__ Qm, const u16* __restrict__ Km,
                                                const u16* __restrict__ Vm, u16* __restrict__ Om) {
  __shared__ u16 Ks[2][64 * 64];
  __shared__ u16 Vs[2][64 * 64];

  const int t = threadIdx.x;
  const int lane = t & 63, w = t >> 6;
  const int lr = lane & 15, g = lane >> 4;
  const int qb = blockIdx.x, pair = blockIdx.y;
  const int b = pair >> 4, a = pair & 15;

  const int qrow = qb * 64 + w * 16 + lr;
  const size_t qoff = ((size_t)(b * 1024 + qrow)) * 1024 + a * 64;
  const short8v qf0 = *(const short8v*)(Qm + qoff + g * 8);
  const short8v qf1 = *(const short8v*)(Qm + qoff + 32 + g * 8);

  float4v z = {0.f, 0.f, 0.f, 0.f};
  float4v ot[4];
#pragma unroll
  for (int i = 0; i < 4; i++) ot[i] = z;
  float mrun = -3.0e38f, lsum = 0.f;

  const u16* Kb = Km + ((size_t)b * 1024) * 1024 + a * 64;
  const u16* Vb = Vm + ((size_t)b * 1024) * 1024 + a * 64;

  const int kr0 = t >> 3, kr1 = kr0 + 32;
  const int kc0 = ((t & 7) ^ (kr0 & 7)) * 8;
  const int vr0 = (t >> 1) & 63;
  const int vc0 = (t >> 7) * 16 + (t & 1) * 8;

#define ASTAGE(u, kt)                                                                                             \
  do {                                                                                                            \
    __builtin_amdgcn_global_load_lds(AS1(Kb + (size_t)((kt) + kr0) * 1024 + kc0), AS3(&Ks[u][t * 8]), 16, 0, 0);  \
    __builtin_amdgcn_global_load_lds(AS1(Kb + (size_t)((kt) + kr1) * 1024 + kc0), AS3(&Ks[u][(t + 256) * 8]),     \
                                     16, 0, 0);                                                                   \
    __builtin_amdgcn_global_load_lds(AS1(Vb + (size_t)((kt) + vr0) * 1024 + vc0), AS3(&Vs[u][t * 8]), 16, 0, 0);  \
    __builtin_amdgcn_global_load_lds(AS1(Vb + (size_t)((kt) + vr0) * 1024 + vc0 + 32), AS3(&Vs[u][(t + 256) * 8]),\
                                     16, 0, 0);                                                                   \
  } while (0)

  const unsigned vsbase = (unsigned)(uintptr_t)AS3(&Vs[0][0]);
  const unsigned vlane = (unsigned)((g * 4 + (lr >> 2)) * 32 + (lane & 3) * 8);

  ASTAGE(0, 0);
  int cur = 0;
  for (int kt = 0; kt < 1024; kt += 64) {
    __syncthreads();
    if (kt + 64 < 1024) ASTAGE(cur ^ 1, kt + 64);

    const u16* Ku = &Ks[cur][0];
    float4v st[4];
#pragma unroll
    for (int jt = 0; jt < 4; jt++) {
      float4v s = z;
      const int row = jt * 16 + lr;
      const int rsw = (row & 7) << 4;
      __builtin_amdgcn_s_setprio(1);
#pragma unroll
      for (int ks = 0; ks < 2; ks++) {
        const int baddr = (row * 128 + (ks * 4 + g) * 16) ^ rsw;
        short8v kf = *(const short8v*)((const char*)Ku + baddr);
        s = MFMA32(kf, ks ? qf1 : qf0, s);
      }
      __builtin_amdgcn_s_setprio(0);
      st[jt] = s;
    }

    float tm = st[0][0];
#pragma unroll
    for (int jt = 0; jt < 4; jt++)
#pragma unroll
      for (int r = 0; r < 4; r++) tm = fmaxf(tm, st[jt][r]);
    tm = fmaxf(tm, __shfl_xor(tm, 16));
    tm = fmaxf(tm, __shfl_xor(tm, 32));
    if (!__all(tm - mrun <= 8.f)) {
      const float mnew = fmaxf(mrun, tm);
      const float sca = exp2f(mrun - mnew);
      lsum *= sca;
#pragma unroll
      for (int d = 0; d < 4; d++)
#pragma unroll
        for (int r = 0; r < 4; r++) ot[d][r] *= sca;
      mrun = mnew;
    }
    float p[16];
    float ts = 0.f;
#pragma unroll
    for (int jt = 0; jt < 4; jt++)
#pragma unroll
      for (int r = 0; r < 4; r++) {
        const float pv = exp2f(st[jt][r] - mrun);
        p[jt * 4 + r] = pv;
        ts += pv;
      }
    ts += __shfl_xor(ts, 16);
    ts += __shfl_xor(ts, 32);
    lsum += ts;

    short4v pf[4];
#pragma unroll
    for (int jt = 0; jt < 4; jt++) {
      unsigned lo = cvtpk(p[jt * 4 + 0], p[jt * 4 + 1]);
      unsigned hi = cvtpk(p[jt * 4 + 2], p[jt * 4 + 3]);
      unsigned u2[2] = {lo, hi};
      pf[jt] = __builtin_bit_cast(short4v, *(unsigned long long*)u2);
    }

    unsigned va = vsbase + (unsigned)cur * 8192u + vlane;
#pragma unroll
    for (int jt = 0; jt < 4; jt++) {
      short4v vf0, vf1, vf2, vf3;
      TR4(vf0, vf1, vf2, vf3, va);
      __builtin_amdgcn_s_setprio(1);
      ot[0] = MFMA16(vf0, pf[jt], ot[0]);
      ot[1] = MFMA16(vf1, pf[jt], ot[1]);
      ot[2] = MFMA16(vf2, pf[jt], ot[2]);
      ot[3] = MFMA16(vf3, pf[jt], ot[3]);
      __builtin_amdgcn_s_setprio(0);
      va += 512u;
    }

    __syncthreads();
    cur ^= 1;
  }
#undef ASTAGE

  const float inv = 1.f / lsum;
  u16* Op = Om + ((size_t)(b * 1024 + qrow)) * 1024 + a * 64;
#pragma unroll
  for (int dblk = 0; dblk < 4; dblk++) {
    short4v o4;
#pragma unroll
    for (int r = 0; r < 4; r++) o4[r] = (short)f2bf(ot[dblk][r] * inv);
    *(short4v*)(Op + dblk * 16 + g * 4) = o4;
  }
}

// ---------------- launch ----------------

extern "C" void kernel_launch(void* const* d_in, const int* in_sizes, int n_in,
                              void* d_out, int out_size, void* d_ws, size_t ws_size,
                              hipStream_t stream) {
  (void)in_sizes; (void)n_in; (void)out_size; (void)ws_size;
  const float* x = (const float*)d_in[0];
  const float* Wq = (const float*)d_in[1];
  const float* bq = (const float*)d_in[2];
  const float* Wk = (const float*)d_in[3];
  const float* bk = (const float*)d_in[4];
  const float* Wv = (const float*)d_in[5];
  const float* bv = (const float*)d_in[6];
  const float* Wo = (const float*)d_in[7];
  const float* bo = (const float*)d_in[8];
  float* out = (float*)d_out;

  char* ws = (char*)d_ws;
  const size_t MB = 1u << 20;
  u16* xb = (u16*)(ws + 0 * MB);
  u16* Wqb = (u16*)(ws + 8 * MB);
  u16* Wkb = (u16*)(ws + 10 * MB);
  u16* Wvb = (u16*)(ws + 12 * MB);
  u16* Wob = (u16*)(ws + 14 * MB);
  u16* Qb = (u16*)(ws + 16 * MB);
  u16* Kb = (u16*)(ws + 24 * MB);
  u16* Vb = (u16*)(ws + 32 * MB);
  u16* Ab = (u16*)(ws + 40 * MB);

  const float csc = 1.4426950408889634f / 8.0f;  // log2(e)/sqrt(HEAD_DIM)

  cast_all<<<dim3(4096, 5), 256, 0, stream>>>(x, Wq, Wk, Wv, Wo, xb, Wqb, Wkb, Wvb, Wob);
  gemm_bt<<<dim3(32, 24), 256, 0, stream>>>(xb, Wqb, Wkb, Wvb, bq, bk, bv, Qb, Kb, Vb, csc, 1.f, 1.f);
  attn_fwd<<<dim3(16, 64), 256, 0, stream>>>(Qb, Kb, Vb, Ab);
  gemm_o64<<<dim3(64, 16), 256, 0, stream>>>(Ab, Wob, bo, out);
}

// Round 8
// 184.492 us; speedup vs baseline: 1.0691x; 1.0032x over previous
//
#include <hip/hip_runtime.h>
#include <stdint.h>

typedef unsigned short u16;
typedef short short4v __attribute__((ext_vector_type(4)));
typedef short short8v __attribute__((ext_vector_type(8)));
typedef float float4v __attribute__((ext_vector_type(4)));

#define AS1(p) ((__attribute__((address_space(1))) void*)(p))
#define AS3(p) ((__attribute__((address_space(3))) void*)(p))

#define MFMA32(a, b, c) __builtin_amdgcn_mfma_f32_16x16x32_bf16(a, b, c, 0, 0, 0)

static __device__ __forceinline__ float4v MFMA16(short4v a, short4v b, float4v c) {
#if __has_builtin(__builtin_amdgcn_mfma_f32_16x16x16bf16_1k)
  return __builtin_amdgcn_mfma_f32_16x16x16bf16_1k(a, b, c, 0, 0, 0);
#else
  float4v d;
  asm volatile("v_mfma_f32_16x16x16_bf16 %0, %1, %2, %3\n\ts_nop 7\n\ts_nop 3"
               : "=v"(d)
               : "v"(a), "v"(b), "v"(c));
  return d;
#endif
}

static __device__ __forceinline__ u16 f2bf(float f) {
  uint32_t u = __builtin_bit_cast(uint32_t, f);
  u += 0x7FFFu + ((u >> 16) & 1u);
  return (u16)(u >> 16);
}

static __device__ __forceinline__ unsigned cvtpk(float lo, float hi) {
  unsigned r;
  asm("v_cvt_pk_bf16_f32 %0, %1, %2" : "=v"(r) : "v"(lo), "v"(hi));
  return r;
}

#define TR4(v0_, v1_, v2_, v3_, addr_)                                   \
  asm volatile("ds_read_b64_tr_b16 %0, %4 offset:0\n\t"                  \
               "ds_read_b64_tr_b16 %1, %4 offset:2048\n\t"               \
               "ds_read_b64_tr_b16 %2, %4 offset:4096\n\t"               \
               "ds_read_b64_tr_b16 %3, %4 offset:6144\n\t"               \
               "s_waitcnt lgkmcnt(0)"                                    \
               : "=&v"(v0_), "=&v"(v1_), "=&v"(v2_), "=&v"(v3_)          \
               : "v"(addr_)                                              \
               : "memory")

// ---------------- fused f32 -> bf16 casts (flat 1-D grid, no empty blocks) ----------------
// blocks 0..4095: x (4M elems); then 4 x 1024 blocks for the weights.

__global__ __launch_bounds__(256) void cast_all(
    const float* __restrict__ x,
    const float* __restrict__ w0, const float* __restrict__ w1,
    const float* __restrict__ w2, const float* __restrict__ w3,
    u16* __restrict__ dx,
    u16* __restrict__ d0, u16* __restrict__ d1,
    u16* __restrict__ d2, u16* __restrict__ d3) {
  int bid = blockIdx.x;
  const float* s;
  u16* d;
  int off;
  if (bid < 4096) {
    s = x; d = dx; off = bid;
  } else {
    const int r = bid - 4096;
    const int wi = r >> 10;
    off = r & 1023;
    switch (wi) {
      case 0: s = w0; d = d0; break;
      case 1: s = w1; d = d1; break;
      case 2: s = w2; d = d2; break;
      default: s = w3; d = d3; break;
    }
  }
  const int i = (off * 256 + threadIdx.x) * 4;
  float4v v = *(const float4v*)(s + i);
  short4v o;
#pragma unroll
  for (int j = 0; j < 4; j++) o[j] = (short)f2bf(v[j]);
  *(short4v*)(d + i) = o;
}

// ---------------- QKV GEMM: 128x128 tile, BK=32, 2-phase dbuf ----------------

__global__ __launch_bounds__(256) void gemm_bt(
    const u16* __restrict__ A,
    const u16* __restrict__ B0, const u16* __restrict__ B1, const u16* __restrict__ B2,
    const float* __restrict__ bias0, const float* __restrict__ bias1, const float* __restrict__ bias2,
    u16* __restrict__ C0, u16* __restrict__ C1, u16* __restrict__ C2,
    float sc0, float sc1, float sc2) {
  constexpr int K = 1024;
  __shared__ u16 As[2][128 * 32];
  __shared__ u16 Bs[2][128 * 32];

  const int t = threadIdx.x;
  const int lane = t & 63, wid = t >> 6;
  const int wr = wid >> 1, wc = wid & 1;
  const int lr = lane & 15, g = lane >> 4;

  const int seg = blockIdx.y >> 3, nb = blockIdx.y & 7, mb = blockIdx.x;
  const u16* B = seg == 0 ? B0 : (seg == 1 ? B1 : B2);
  const float* bias = seg == 0 ? bias0 : (seg == 1 ? bias1 : bias2);
  u16* C = seg == 0 ? C0 : (seg == 1 ? C1 : C2);
  const float scale = seg == 0 ? sc0 : (seg == 1 ? sc1 : sc2);

  const u16* Ap = A + (size_t)mb * 128 * K;
  const u16* Bp = B + (size_t)nb * 128 * K;

  float4v z = {0.f, 0.f, 0.f, 0.f};
  float4v acc[4][4];
#pragma unroll
  for (int i = 0; i < 4; i++)
#pragma unroll
    for (int j = 0; j < 4; j++) acc[i][j] = z;

  const int r0 = t >> 2, c0 = (t & 3) * 8;

#define GSTAGE(u, kk)                                                                                          \
  do {                                                                                                         \
    __builtin_amdgcn_global_load_lds(AS1(Ap + (size_t)r0 * K + (kk) + c0), AS3(&As[u][t * 8]), 16, 0, 0);      \
    __builtin_amdgcn_global_load_lds(AS1(Ap + (size_t)(r0 + 64) * K + (kk) + c0), AS3(&As[u][(t + 256) * 8]),  \
                                     16, 0, 0);                                                                \
    __builtin_amdgcn_global_load_lds(AS1(Bp + (size_t)r0 * K + (kk) + c0), AS3(&Bs[u][t * 8]), 16, 0, 0);      \
    __builtin_amdgcn_global_load_lds(AS1(Bp + (size_t)(r0 + 64) * K + (kk) + c0), AS3(&Bs[u][(t + 256) * 8]),  \
                                     16, 0, 0);                                                                \
  } while (0)

  GSTAGE(0, 0);
  int cur = 0;
  for (int k0 = 0; k0 < K; k0 += 32) {
    __syncthreads();
    if (k0 + 32 < K) GSTAGE(cur ^ 1, k0 + 32);

    const u16* Au = &As[cur][0];
    const u16* Bu = &Bs[cur][0];
    short8v af[4], bfr[4];
#pragma unroll
    for (int mi = 0; mi < 4; mi++) af[mi] = *(const short8v*)(Au + (wr * 64 + mi * 16 + lr) * 32 + g * 8);
#pragma unroll
    for (int ni = 0; ni < 4; ni++) bfr[ni] = *(const short8v*)(Bu + (wc * 64 + ni * 16 + lr) * 32 + g * 8);
    __builtin_amdgcn_s_setprio(1);
#pragma unroll
    for (int mi = 0; mi < 4; mi++)
#pragma unroll
      for (int ni = 0; ni < 4; ni++) acc[mi][ni] = MFMA32(af[mi], bfr[ni], acc[mi][ni]);
    __builtin_amdgcn_s_setprio(0);
    __syncthreads();
    cur ^= 1;
  }
#undef GSTAGE

  const int colb = nb * 128 + wc * 64;
  const int rowb = mb * 128 + wr * 64;
#pragma unroll
  for (int ni = 0; ni < 4; ni++) {
    const int col = colb + ni * 16 + lr;
    const float bv = bias[col];
#pragma unroll
    for (int mi = 0; mi < 4; mi++) {
      const int row0 = rowb + mi * 16 + g * 4;
      float4v a = acc[mi][ni];
#pragma unroll
      for (int r = 0; r < 4; r++) C[(size_t)(row0 + r) * 1024 + col] = f2bf((a[r] + bv) * scale);
    }
  }
}

// ---------------- O-projection GEMM: 64x64 tile, BK=32, 2-phase dbuf ----------------

__global__ __launch_bounds__(256) void gemm_o64(const u16* __restrict__ A, const u16* __restrict__ B,
                                                const float* __restrict__ bias, float* __restrict__ C) {
  constexpr int K = 1024;
  __shared__ u16 As[2][64 * 32];
  __shared__ u16 Bs[2][64 * 32];

  const int t = threadIdx.x;
  const int lane = t & 63, wid = t >> 6;
  const int wr = wid >> 1, wc = wid & 1;  // 2x2 waves; wave tile 32x32
  const int lr = lane & 15, g = lane >> 4;

  const int mb = blockIdx.x, nb = blockIdx.y;
  const u16* Ap = A + (size_t)mb * 64 * K;
  const u16* Bp = B + (size_t)nb * 64 * K;

  float4v z = {0.f, 0.f, 0.f, 0.f};
  float4v acc[2][2];
#pragma unroll
  for (int i = 0; i < 2; i++)
#pragma unroll
    for (int j = 0; j < 2; j++) acc[i][j] = z;

  const int r0 = t >> 2, c0 = (t & 3) * 8;

#define OSTAGE(u, kk)                                                                                       \
  do {                                                                                                      \
    __builtin_amdgcn_global_load_lds(AS1(Ap + (size_t)r0 * K + (kk) + c0), AS3(&As[u][t * 8]), 16, 0, 0);   \
    __builtin_amdgcn_global_load_lds(AS1(Bp + (size_t)r0 * K + (kk) + c0), AS3(&Bs[u][t * 8]), 16, 0, 0);   \
  } while (0)

  OSTAGE(0, 0);
  int cur = 0;
  for (int k0 = 0; k0 < K; k0 += 32) {
    __syncthreads();
    if (k0 + 32 < K) OSTAGE(cur ^ 1, k0 + 32);

    const u16* Au = &As[cur][0];
    const u16* Bu = &Bs[cur][0];
    short8v af[2], bfr[2];
#pragma unroll
    for (int mi = 0; mi < 2; mi++) af[mi] = *(const short8v*)(Au + (wr * 32 + mi * 16 + lr) * 32 + g * 8);
#pragma unroll
    for (int ni = 0; ni < 2; ni++) bfr[ni] = *(const short8v*)(Bu + (wc * 32 + ni * 16 + lr) * 32 + g * 8);
    __builtin_amdgcn_s_setprio(1);
#pragma unroll
    for (int mi = 0; mi < 2; mi++)
#pragma unroll
      for (int ni = 0; ni < 2; ni++) acc[mi][ni] = MFMA32(af[mi], bfr[ni], acc[mi][ni]);
    __builtin_amdgcn_s_setprio(0);
    __syncthreads();
    cur ^= 1;
  }
#undef OSTAGE

  const int colb = nb * 64 + wc * 32;
  const int rowb = mb * 64 + wr * 32;
#pragma unroll
  for (int ni = 0; ni < 2; ni++) {
    const int col = colb + ni * 16 + lr;
    const float bv = bias[col];
#pragma unroll
    for (int mi = 0; mi < 2; mi++) {
      const int row0 = rowb + mi * 16 + g * 4;
#pragma unroll
      for (int r = 0; r < 4; r++) C[(size_t)(row0 + r) * 1024 + col] = acc[mi][ni][r] + bv;
    }
  }
}

// ---------------- Flash attention (QBLK=64, KVBLK=64, dbuf) ----------------
// R8: softmax denominator via ones-column MFMA (Σ_k P on the matrix pipe —
// removes 16 adds + 2 shfls/tile from the VALU) + tree max (breaks the serial
// 15-deep fmax chain). Denominator sums the same bf16-rounded P used in the
// numerator (consistent rounding).

__global__ __launch_bounds__(256) void attn_fwd(const u16* __restrict__ Qm, const u16* __restrict__ Km,
                                                const u16* __restrict__ Vm, u16* __restrict__ Om) {
  __shared__ u16 Ks[2][64 * 64];
  __shared__ u16 Vs[2][64 * 64];

  const int t = threadIdx.x;
  const int lane = t & 63, w = t >> 6;
  const int lr = lane & 15, g = lane >> 4;
  const int qb = blockIdx.x, pair = blockIdx.y;
  const int b = pair >> 4, a = pair & 15;

  const int qrow = qb * 64 + w * 16 + lr;
  const size_t qoff = ((size_t)(b * 1024 + qrow)) * 1024 + a * 64;
  const short8v qf0 = *(const short8v*)(Qm + qoff + g * 8);
  const short8v qf1 = *(const short8v*)(Qm + qoff + 32 + g * 8);

  float4v z = {0.f, 0.f, 0.f, 0.f};
  float4v ot[4];
#pragma unroll
  for (int i = 0; i < 4; i++) ot[i] = z;
  float4v osum = z;  // ones-column accumulator: every reg = Σ_k P[k][q=lr]
  float mrun = -3.0e38f;
  const short one_bf = (short)0x3F80;  // bf16 1.0
  const short4v ones4 = {one_bf, one_bf, one_bf, one_bf};

  const u16* Kb = Km + ((size_t)b * 1024) * 1024 + a * 64;
  const u16* Vb = Vm + ((size_t)b * 1024) * 1024 + a * 64;

  const int kr0 = t >> 3, kr1 = kr0 + 32;
  const int kc0 = ((t & 7) ^ (kr0 & 7)) * 8;
  const int vr0 = (t >> 1) & 63;
  const int vc0 = (t >> 7) * 16 + (t & 1) * 8;

#define ASTAGE(u, kt)                                                                                             \
  do {                                                                                                            \
    __builtin_amdgcn_global_load_lds(AS1(Kb + (size_t)((kt) + kr0) * 1024 + kc0), AS3(&Ks[u][t * 8]), 16, 0, 0);  \
    __builtin_amdgcn_global_load_lds(AS1(Kb + (size_t)((kt) + kr1) * 1024 + kc0), AS3(&Ks[u][(t + 256) * 8]),     \
                                     16, 0, 0);                                                                   \
    __builtin_amdgcn_global_load_lds(AS1(Vb + (size_t)((kt) + vr0) * 1024 + vc0), AS3(&Vs[u][t * 8]), 16, 0, 0);  \
    __builtin_amdgcn_global_load_lds(AS1(Vb + (size_t)((kt) + vr0) * 1024 + vc0 + 32), AS3(&Vs[u][(t + 256) * 8]),\
                                     16, 0, 0);                                                                   \
  } while (0)

  const unsigned vsbase = (unsigned)(uintptr_t)AS3(&Vs[0][0]);
  const unsigned vlane = (unsigned)((g * 4 + (lr >> 2)) * 32 + (lane & 3) * 8);

  ASTAGE(0, 0);
  int cur = 0;
  for (int kt = 0; kt < 1024; kt += 64) {
    __syncthreads();
    if (kt + 64 < 1024) ASTAGE(cur ^ 1, kt + 64);

    const u16* Ku = &Ks[cur][0];
    float4v st[4];
#pragma unroll
    for (int jt = 0; jt < 4; jt++) {
      float4v s = z;
      const int row = jt * 16 + lr;
      const int rsw = (row & 7) << 4;
      __builtin_amdgcn_s_setprio(1);
#pragma unroll
      for (int ks = 0; ks < 2; ks++) {
        const int baddr = (row * 128 + (ks * 4 + g) * 16) ^ rsw;
        short8v kf = *(const short8v*)((const char*)Ku + baddr);
        s = MFMA32(kf, ks ? qf1 : qf0, s);
      }
      __builtin_amdgcn_s_setprio(0);
      st[jt] = s;
    }

    // tree max (depth 4, ILP; clang fuses pairs to v_max3 where possible)
    float x0 = fmaxf(fmaxf(st[0][0], st[0][1]), fmaxf(st[0][2], st[0][3]));
    float x1 = fmaxf(fmaxf(st[1][0], st[1][1]), fmaxf(st[1][2], st[1][3]));
    float x2 = fmaxf(fmaxf(st[2][0], st[2][1]), fmaxf(st[2][2], st[2][3]));
    float x3 = fmaxf(fmaxf(st[3][0], st[3][1]), fmaxf(st[3][2], st[3][3]));
    float tm = fmaxf(fmaxf(x0, x1), fmaxf(x2, x3));
    tm = fmaxf(tm, __shfl_xor(tm, 16));
    tm = fmaxf(tm, __shfl_xor(tm, 32));
    if (!__all(tm - mrun <= 8.f)) {  // T13 defer-max
      const float mnew = fmaxf(mrun, tm);
      const float sca = exp2f(mrun - mnew);
#pragma unroll
      for (int d = 0; d < 4; d++)
#pragma unroll
        for (int r = 0; r < 4; r++) ot[d][r] *= sca;
#pragma unroll
      for (int r = 0; r < 4; r++) osum[r] *= sca;
      mrun = mnew;
    }
    float p[16];
#pragma unroll
    for (int jt = 0; jt < 4; jt++)
#pragma unroll
      for (int r = 0; r < 4; r++) p[jt * 4 + r] = exp2f(st[jt][r] - mrun);

    short4v pf[4];
#pragma unroll
    for (int jt = 0; jt < 4; jt++) {
      unsigned lo = cvtpk(p[jt * 4 + 0], p[jt * 4 + 1]);
      unsigned hi = cvtpk(p[jt * 4 + 2], p[jt * 4 + 3]);
      unsigned u2[2] = {lo, hi};
      pf[jt] = __builtin_bit_cast(short4v, *(unsigned long long*)u2);
    }

    unsigned va = vsbase + (unsigned)cur * 8192u + vlane;
#pragma unroll
    for (int jt = 0; jt < 4; jt++) {
      short4v vf0, vf1, vf2, vf3;
      TR4(vf0, vf1, vf2, vf3, va);
      __builtin_amdgcn_s_setprio(1);
      ot[0] = MFMA16(vf0, pf[jt], ot[0]);
      ot[1] = MFMA16(vf1, pf[jt], ot[1]);
      ot[2] = MFMA16(vf2, pf[jt], ot[2]);
      ot[3] = MFMA16(vf3, pf[jt], ot[3]);
      osum = MFMA16(ones4, pf[jt], osum);  // denominator on the MFMA pipe
      __builtin_amdgcn_s_setprio(0);
      va += 512u;
    }

    __syncthreads();
    cur ^= 1;
  }
#undef ASTAGE

  const float inv = 1.f / osum[0];
  u16* Op = Om + ((size_t)(b * 1024 + qrow)) * 1024 + a * 64;
#pragma unroll
  for (int dblk = 0; dblk < 4; dblk++) {
    short4v o4;
#pragma unroll
    for (int r = 0; r < 4; r++) o4[r] = (short)f2bf(ot[dblk][r] * inv);
    *(short4v*)(Op + dblk * 16 + g * 4) = o4;
  }
}

// ---------------- launch ----------------

extern "C" void kernel_launch(void* const* d_in, const int* in_sizes, int n_in,
                              void* d_out, int out_size, void* d_ws, size_t ws_size,
                              hipStream_t stream) {
  (void)in_sizes; (void)n_in; (void)out_size; (void)ws_size;
  const float* x = (const float*)d_in[0];
  const float* Wq = (const float*)d_in[1];
  const float* bq = (const float*)d_in[2];
  const float* Wk = (const float*)d_in[3];
  const float* bk = (const float*)d_in[4];
  const float* Wv = (const float*)d_in[5];
  const float* bv = (const float*)d_in[6];
  const float* Wo = (const float*)d_in[7];
  const float* bo = (const float*)d_in[8];
  float* out = (float*)d_out;

  char* ws = (char*)d_ws;
  const size_t MB = 1u << 20;
  u16* xb = (u16*)(ws + 0 * MB);
  u16* Wqb = (u16*)(ws + 8 * MB);
  u16* Wkb = (u16*)(ws + 10 * MB);
  u16* Wvb = (u16*)(ws + 12 * MB);
  u16* Wob = (u16*)(ws + 14 * MB);
  u16* Qb = (u16*)(ws + 16 * MB);
  u16* Kb = (u16*)(ws + 24 * MB);
  u16* Vb = (u16*)(ws + 32 * MB);
  u16* Ab = (u16*)(ws + 40 * MB);

  const float csc = 1.4426950408889634f / 8.0f;  // log2(e)/sqrt(HEAD_DIM)

  cast_all<<<8192, 256, 0, stream>>>(x, Wq, Wk, Wv, Wo, xb, Wqb, Wkb, Wvb, Wob);
  gemm_bt<<<dim3(32, 24), 256, 0, stream>>>(xb, Wqb, Wkb, Wvb, bq, bk, bv, Qb, Kb, Vb, csc, 1.f, 1.f);
  attn_fwd<<<dim3(16, 64), 256, 0, stream>>>(Qb, Kb, Vb, Ab);
  gemm_o64<<<dim3(64, 16), 256, 0, stream>>>(Ab, Wob, bo, out);
}